// Round 5
// baseline (79461.755 us; speedup 1.0000x reference)
//
#include <hip/hip_runtime.h>
#include <hip/hip_bf16.h>
#include <stdint.h>

#define TD 128   // decoder steps
#define NB 16    // batch
#define TE 512   // encoder time
#define EE 512   // encoder dim
#define HH 1024  // hidden
#define G4 4096  // 4*H
#define NM 80    // mel bins
#define PP 256   // prenet dim

// ---------------- Threefry-2x32 (exact JAX schedule) ----------------
__host__ __device__ inline void threefry2x32(uint32_t k0, uint32_t k1,
                                             uint32_t& x0, uint32_t& x1) {
  uint32_t ks0 = k0, ks1 = k1, ks2 = k0 ^ k1 ^ 0x1BD11BDAu;
  x0 += ks0; x1 += ks1;
#define RND(rot) { x0 += x1; x1 = (x1 << (rot)) | (x1 >> (32 - (rot))); x1 ^= x0; }
  RND(13) RND(15) RND(26) RND(6)
  x0 += ks1; x1 += ks2 + 1u;
  RND(17) RND(29) RND(16) RND(24)
  x0 += ks2; x1 += ks0 + 2u;
  RND(13) RND(15) RND(26) RND(6)
  x0 += ks0; x1 += ks1 + 3u;
  RND(17) RND(29) RND(16) RND(24)
  x0 += ks1; x1 += ks2 + 4u;
  RND(13) RND(15) RND(26) RND(6)
  x0 += ks2; x1 += ks0 + 5u;
#undef RND
}

__device__ inline double dsig(double x) { return 1.0 / (1.0 + exp(-x)); }

// dropout mask for flat index i under key (ka,kb).
// JAX partitionable threefry random_bits, bit_width=32 (jax/_src/prng.py):
//   counts1, counts2 = iota_2x32_shape(shape)      -> (0, i) for size < 2^32
//   bits1, bits2 = threefry2x32_p.bind(k1,k2,counts1,counts2)
//   return convert_element_type(bits1 ^ bits2, uint32)   <-- XOR of both words
__device__ inline double mask_val(uint32_t ka, uint32_t kb, uint32_t i) {
  uint32_t x0 = 0u, x1 = i;
  threefry2x32(ka, kb, x0, x1);
  uint32_t bits = x0 ^ x1;
  float u = __uint_as_float((bits >> 9) | 0x3f800000u) - 1.0f;
  return (u < 0.5f) ? 2.0 : 0.0;
}

// ---------------- precompute: proc_enc (transposed [b][d][t], fp64) ----------------
__global__ void k_proc_enc(const float* __restrict__ inputs,
                           const float* __restrict__ W_enc,
                           double* __restrict__ procT) {
  int blk = blockIdx.x;          // 512 = 16 b * 32 t-tiles
  int b = blk >> 5;
  int t0 = (blk & 31) * 16;
  int d = threadIdx.x;           // 128
  __shared__ float in_l[16][EE];
  for (int idx = threadIdx.x; idx < 16 * EE; idx += blockDim.x) {
    int tt = idx >> 9, e = idx & 511;
    in_l[tt][e] = inputs[((size_t)(b * TE + t0 + tt)) * EE + e];
  }
  __syncthreads();
  double acc[16];
#pragma unroll
  for (int tt = 0; tt < 16; ++tt) acc[tt] = 0.0;
  const float* wr = W_enc + (size_t)d * EE;
  for (int e = 0; e < EE; ++e) {
    double w = (double)wr[e];
#pragma unroll
    for (int tt = 0; tt < 16; ++tt) acc[tt] += w * (double)in_l[tt][e];
  }
  for (int tt = 0; tt < 16; ++tt)
    procT[((size_t)(b * 128 + d)) * TE + t0 + tt] = acc[tt];
}

// ---------------- precompute: prenet p for all (s,b), masks inline ----------------
__global__ void k_p(const float* __restrict__ pm, const float* __restrict__ Wp1,
                    const float* __restrict__ Wp2,
                    uint32_t k1a, uint32_t k1b, uint32_t k2a, uint32_t k2b,
                    double* __restrict__ p_all) {
  int sb = blockIdx.x;           // s*16+b, 2048 blocks
  int s = sb >> 4, b = sb & 15;
  int tid = threadIdx.x;         // 256
  uint32_t mi = (uint32_t)(sb * PP + tid);
  double d1 = mask_val(k1a, k1b, mi);
  double d2 = mask_val(k2a, k2b, mi);
  __shared__ float x_l[NM];
  __shared__ double p1_l[PP];
  if (tid < NM) x_l[tid] = (s == 0) ? 0.f : pm[(b * NM + tid) * TD + (s - 1)];
  __syncthreads();
  double a = 0.0;
  const float* w1 = Wp1 + tid * NM;
  for (int m = 0; m < NM; ++m) a += (double)w1[m] * (double)x_l[m];
  a = fmax(a, 0.0) * d1;
  p1_l[tid] = a;
  __syncthreads();
  double c = 0.0;
  const float* w2 = Wp2 + tid * PP;
  for (int k = 0; k < PP; ++k) c += (double)w2[k] * p1_l[k];
  c = fmax(c, 0.0) * d2;
  p_all[sb * PP + tid] = c;
}

__global__ void k_init(double* __restrict__ cum, double* __restrict__ ctx) {
  for (int i = threadIdx.x; i < NB * TE; i += blockDim.x) cum[i] = 0.0;
  for (int i = threadIdx.x; i < NB * EE; i += blockDim.x) ctx[i] = 0.0;
}

// ---------------- per step: g1 = b_ih1+b_hh1 + Wih1 @ [p, ctx], zero state ----------------
__global__ void k_step_pre(int s, const float* __restrict__ Wih1,
                           const float* __restrict__ bih1, const float* __restrict__ bhh1,
                           const double* __restrict__ p_all, const double* __restrict__ ctx,
                           double* __restrict__ g1full,
                           double* __restrict__ h1buf, double* __restrict__ h2buf,
                           double* __restrict__ c1, double* __restrict__ c2) {
  int w = blockIdx.x;            // 256
  int tid = threadIdx.x;         // 256
  int r = tid & 15, b = tid >> 4;
  int row = w * 16 + r;
  const float* wr = Wih1 + (size_t)row * 768;
  const double* pv = p_all + (s * NB + b) * PP;
  const double* cv = ctx + b * EE;
  double acc = (double)bih1[row] + (double)bhh1[row];
  for (int k = 0; k < PP; ++k) acc += (double)wr[k] * pv[k];
  for (int e = 0; e < EE; ++e) acc += (double)wr[PP + e] * cv[e];
  g1full[b * G4 + row] = acc;
  if (w == 0) {
    for (int i = tid; i < HH; i += 256) {
      h1buf[i] = 0.0; h2buf[i] = 0.0; c1[i] = 0.0; c2[i] = 0.0;
    }
  }
}

// ---------------- LSTM layer-1 cell for item b ----------------
__global__ void k_cell1(int b, const float* __restrict__ Whh1,
                        const double* __restrict__ g1full,
                        double* __restrict__ h1buf, double* __restrict__ c1) {
  int w = blockIdx.x, tid = threadIdx.x;   // 256 wgs x 256 thr
  int r = tid >> 4, lane = tid & 15;
  int jj = w * 4 + (r & 3), gate = r >> 2;
  int row = gate * HH + jj;
  const float4* wr = (const float4*)(Whh1 + (size_t)row * HH);
  const double* hv = h1buf + (b & 1) * HH;
  double acc = 0.0;
#pragma unroll
  for (int i = 0; i < 16; ++i) {
    float4 wv = wr[i * 16 + lane];
    int k = (i * 16 + lane) * 4;
    acc += (double)wv.x * hv[k] + (double)wv.y * hv[k + 1]
         + (double)wv.z * hv[k + 2] + (double)wv.w * hv[k + 3];
  }
#pragma unroll
  for (int m = 8; m >= 1; m >>= 1) acc += __shfl_xor(acc, m);
  __shared__ double gsum[16];
  if (lane == 0) gsum[r] = acc + g1full[b * G4 + row];
  __syncthreads();
  if (tid < 4) {
    int j = w * 4 + tid;
    double gi = gsum[tid], gf = gsum[4 + tid], gg = gsum[8 + tid], go = gsum[12 + tid];
    double cn = dsig(gf) * c1[j] + dsig(gi) * tanh(gg);
    double hn = dsig(go) * tanh(cn);
    c1[j] = cn;
    h1buf[((b + 1) & 1) * HH + j] = hn;
  }
}

// ---------------- LSTM layer-2 cell for item b ----------------
__global__ void k_cell2(int b, const float* __restrict__ Wih2,
                        const float* __restrict__ Whh2,
                        const float* __restrict__ bih2, const float* __restrict__ bhh2,
                        const double* __restrict__ h1buf, double* __restrict__ h2buf,
                        double* __restrict__ c2, double* __restrict__ h_all) {
  int w = blockIdx.x, tid = threadIdx.x;
  int r = tid >> 4, lane = tid & 15;
  int jj = w * 4 + (r & 3), gate = r >> 2;
  int row = gate * HH + jj;
  const float4* wi = (const float4*)(Wih2 + (size_t)row * HH);
  const float4* wh = (const float4*)(Whh2 + (size_t)row * HH);
  const double* x1 = h1buf + ((b + 1) & 1) * HH;
  const double* x2 = h2buf + (b & 1) * HH;
  double acc = 0.0;
#pragma unroll
  for (int i = 0; i < 16; ++i) {
    float4 wv = wi[i * 16 + lane];
    int k = (i * 16 + lane) * 4;
    acc += (double)wv.x * x1[k] + (double)wv.y * x1[k + 1]
         + (double)wv.z * x1[k + 2] + (double)wv.w * x1[k + 3];
  }
#pragma unroll
  for (int i = 0; i < 16; ++i) {
    float4 wv = wh[i * 16 + lane];
    int k = (i * 16 + lane) * 4;
    acc += (double)wv.x * x2[k] + (double)wv.y * x2[k + 1]
         + (double)wv.z * x2[k + 2] + (double)wv.w * x2[k + 3];
  }
#pragma unroll
  for (int m = 8; m >= 1; m >>= 1) acc += __shfl_xor(acc, m);
  __shared__ double gsum[16];
  if (lane == 0) gsum[r] = acc + (double)bih2[row] + (double)bhh2[row];
  __syncthreads();
  if (tid < 4) {
    int j = w * 4 + tid;
    double gi = gsum[tid], gf = gsum[4 + tid], gg = gsum[8 + tid], go = gsum[12 + tid];
    double cn = dsig(gf) * c2[j] + dsig(gi) * tanh(gg);
    double hn = dsig(go) * tanh(cn);
    c2[j] = cn;
    h2buf[((b + 1) & 1) * HH + j] = hn;
    h_all[b * HH + j] = hn;
  }
}

// ---------------- attention energies ----------------
__global__ void k_att1(const float* __restrict__ Wq, const double* __restrict__ h_all,
                       const float* __restrict__ Wlc, const float* __restrict__ blc,
                       const float* __restrict__ Wld, const float* __restrict__ bld,
                       const float* __restrict__ we, const float* __restrict__ be,
                       const double* __restrict__ cum, const double* __restrict__ procT,
                       double* __restrict__ e_aw) {
  int blk = blockIdx.x;          // 64 wgs
  int b = blk >> 2;
  int t0 = (blk & 3) * 128;
  int tid = threadIdx.x;         // 128
  __shared__ double q_l[128], wld_l[4096], wcl[992], we_l[128], bld_l[128],
                    blc_l[32], cum_l[158];
  {
    const double* hb = h_all + b * HH;
    const float* wq = Wq + (size_t)tid * HH;
    double a = 0.0;
    for (int k = 0; k < HH; ++k) a += (double)wq[k] * hb[k];
    q_l[tid] = a;
  }
  for (int i = tid; i < 4096; i += 128) wld_l[i] = (double)Wld[i];
  for (int i = tid; i < 992; i += 128) wcl[i] = (double)Wlc[i];
  we_l[tid] = (double)we[tid];
  bld_l[tid] = (double)bld[tid];
  if (tid < 32) blc_l[tid] = (double)blc[tid];
  for (int i = tid; i < 158; i += 128) {
    int g = t0 - 15 + i;
    cum_l[i] = (g >= 0 && g < TE) ? cum[b * TE + g] : 0.0;
  }
  __syncthreads();
  int t = t0 + tid;
  double loc32[32];
#pragma unroll
  for (int c = 0; c < 32; ++c) {
    double v = blc_l[c];
    const double* wc = wcl + c * 31;
#pragma unroll
    for (int k = 0; k < 31; ++k) v += wc[k] * cum_l[tid + k];
    loc32[c] = v;
  }
  double en = 0.0;
  const double* pe = procT + ((size_t)b * 128) * TE + t;
  for (int d = 0; d < 128; ++d) {
    double sv = q_l[d] + bld_l[d] + pe[(size_t)d * TE];
    const double* wd = wld_l + d * 32;
#pragma unroll
    for (int c = 0; c < 32; ++c) sv += loc32[c] * wd[c];
    en += tanh(sv) * we_l[d];
  }
  e_aw[b * TE + t] = en + (double)be[0];
}

// ---------------- softmax + cum update (aw in place) ----------------
__global__ void k_soft(double* __restrict__ e_aw, double* __restrict__ cum) {
  int b = blockIdx.x, tid = threadIdx.x;  // 16 x 256
  __shared__ double red[256];
  double e0 = e_aw[b * TE + tid], e1 = e_aw[b * TE + 256 + tid];
  red[tid] = fmax(e0, e1); __syncthreads();
  for (int s = 128; s > 0; s >>= 1) {
    if (tid < s) red[tid] = fmax(red[tid], red[tid + s]);
    __syncthreads();
  }
  double mx = red[0]; __syncthreads();
  double p0 = exp(e0 - mx), p1 = exp(e1 - mx);
  red[tid] = p0 + p1; __syncthreads();
  for (int s = 128; s > 0; s >>= 1) {
    if (tid < s) red[tid] += red[tid + s];
    __syncthreads();
  }
  double inv = 1.0 / red[0];
  double a0 = p0 * inv, a1 = p1 * inv;
  e_aw[b * TE + tid] = a0; e_aw[b * TE + 256 + tid] = a1;
  cum[b * TE + tid] += a0; cum[b * TE + 256 + tid] += a1;
}

// ---------------- context = aw @ inputs ----------------
__global__ void k_ctx(const float* __restrict__ inputs, const double* __restrict__ e_aw,
                      double* __restrict__ ctx) {
  int blk = blockIdx.x;          // 128
  int b = blk >> 3, ee0 = (blk & 7) * 64;
  int tid = threadIdx.x;         // 256
  int ee = ee0 + (tid & 63), tp = tid >> 6;
  __shared__ double aw_l[TE];
  __shared__ double red[256];
  for (int i = tid; i < TE; i += 256) aw_l[i] = e_aw[b * TE + i];
  __syncthreads();
  double acc = 0.0;
  const float* ip = inputs + ((size_t)b * TE) * EE + ee;
  for (int t = tp * 128; t < tp * 128 + 128; ++t)
    acc += aw_l[t] * (double)ip[(size_t)t * EE];
  red[tid] = acc; __syncthreads();
  if (tp == 0) {
    double v = red[tid] + red[tid + 64] + red[tid + 128] + red[tid + 192];
    ctx[b * EE + ee] = v;
  }
}

// ---------------- frame + stop outputs ----------------
__global__ void k_out(int s, const float* __restrict__ Wproj, const float* __restrict__ bproj,
                      const float* __restrict__ Wstop, const float* __restrict__ bstop,
                      const double* __restrict__ h_all, const double* __restrict__ ctx,
                      float* __restrict__ out) {
  int b = blockIdx.x, tid = threadIdx.x;   // 16 x 256
  int o = tid >> 1, part = tid & 1;
  const double* hb = h_all + b * HH;
  const double* cb = ctx + b * EE;
  double acc = 0.0;
  if (o < NM) {
    const float* wr = Wproj + (size_t)o * 1536 + part * 768;
    if (part == 0) {
      acc = (double)bproj[o];
      for (int k = 0; k < 768; ++k) acc += (double)wr[k] * hb[k];
    } else {
      for (int k = 0; k < 256; ++k) acc += (double)wr[k] * hb[768 + k];
      for (int k = 0; k < 512; ++k) acc += (double)wr[256 + k] * cb[k];
    }
  } else if (o == NM) {
    const float* wr = Wstop + part * 768;
    if (part == 0) {
      acc = (double)bstop[0];
      for (int k = 0; k < 768; ++k) acc += (double)wr[k] * hb[k];
    } else {
      for (int k = 0; k < 256; ++k) acc += (double)wr[k] * hb[768 + k];
      for (int k = 0; k < 512; ++k) acc += (double)wr[256 + k] * cb[k];
    }
  }
  acc += __shfl_xor(acc, 1);
  if (part == 0) {
    if (o < NM)      out[((size_t)b * TD + s) * NM + o] = (float)acc;
    else if (o == NM) out[(size_t)NB * TD * NM + b * TD + s] = (float)acc;
  }
}

extern "C" void kernel_launch(void* const* d_in, const int* in_sizes, int n_in,
                              void* d_out, int out_size, void* d_ws, size_t ws_size,
                              hipStream_t stream) {
  const float* inputs = (const float*)d_in[0];
  const float* pmels  = (const float*)d_in[1];
  const float* W_enc  = (const float*)d_in[2];
  const float* W_q    = (const float*)d_in[3];
  const float* W_lc   = (const float*)d_in[4];
  const float* b_lc   = (const float*)d_in[5];
  const float* W_ld   = (const float*)d_in[6];
  const float* b_ld   = (const float*)d_in[7];
  const float* w_e    = (const float*)d_in[8];
  const float* b_e    = (const float*)d_in[9];
  const float* W_p1   = (const float*)d_in[10];
  const float* W_p2   = (const float*)d_in[11];
  const float* W_ih1  = (const float*)d_in[12];
  const float* W_hh1  = (const float*)d_in[13];
  const float* b_ih1  = (const float*)d_in[14];
  const float* b_hh1  = (const float*)d_in[15];
  const float* W_ih2  = (const float*)d_in[16];
  const float* W_hh2  = (const float*)d_in[17];
  const float* b_ih2  = (const float*)d_in[18];
  const float* b_hh2  = (const float*)d_in[19];
  const float* W_proj = (const float*)d_in[20];
  const float* b_proj = (const float*)d_in[21];
  const float* W_stop = (const float*)d_in[22];
  const float* b_stop = (const float*)d_in[23];
  float* out = (float*)d_out;

  double* ws    = (double*)d_ws;
  double* p_all = ws;                 // 524288
  double* procT = p_all + 524288;     // 1048576
  double* g1full= procT + 1048576;    // 65536
  double* h1buf = g1full + 65536;     // 2048 (ping-pong)
  double* h2buf = h1buf + 2048;       // 2048
  double* c1    = h2buf + 2048;       // 1024
  double* c2    = c1 + 1024;          // 1024
  double* h_all = c2 + 1024;          // 16384
  double* e_aw  = h_all + 16384;      // 8192
  double* cum   = e_aw + 8192;        // 8192
  double* ctx   = cum + 8192;         // 8192
  // total ~1.69M doubles (~13.5 MB)

  // fold_in keys on host: key(42) = (0,42); fold_in data 0 / 1
  uint32_t k1a = 0u, k1b = 0u, k2a = 0u, k2b = 1u;
  threefry2x32(0u, 42u, k1a, k1b);
  threefry2x32(0u, 42u, k2a, k2b);

  k_proc_enc<<<512, 128, 0, stream>>>(inputs, W_enc, procT);
  k_p<<<TD * NB, 256, 0, stream>>>(pmels, W_p1, W_p2, k1a, k1b, k2a, k2b, p_all);
  k_init<<<1, 256, 0, stream>>>(cum, ctx);

  for (int s = 0; s < TD; ++s) {
    k_step_pre<<<256, 256, 0, stream>>>(s, W_ih1, b_ih1, b_hh1, p_all, ctx,
                                        g1full, h1buf, h2buf, c1, c2);
    for (int b = 0; b < NB; ++b) {
      k_cell1<<<256, 256, 0, stream>>>(b, W_hh1, g1full, h1buf, c1);
      k_cell2<<<256, 256, 0, stream>>>(b, W_ih2, W_hh2, b_ih2, b_hh2,
                                       h1buf, h2buf, c2, h_all);
    }
    k_att1<<<64, 128, 0, stream>>>(W_q, h_all, W_lc, b_lc, W_ld, b_ld, w_e, b_e,
                                   cum, procT, e_aw);
    k_soft<<<16, 256, 0, stream>>>(e_aw, cum);
    k_ctx<<<128, 256, 0, stream>>>(inputs, e_aw, ctx);
    k_out<<<16, 256, 0, stream>>>(s, W_proj, b_proj, W_stop, b_stop, h_all, ctx, out);
  }
  (void)in_sizes; (void)n_in; (void)out_size; (void)ws_size;
}